// Round 6
// baseline (206.600 us; speedup 1.0000x reference)
//
#include <hip/hip_runtime.h>

// y_pred: [2, 2, 128, 256, 256] f32   y_true: [2, 128, 256, 256] i32
// C=2 -> only channel 1 of y_pred is read; op reduces to 3 counters
// ct=#(yt==1), cp=#(p>0.5), cb=#(both). Outputs are closed forms.
//
// R6: R5 structure (fused NT-load count kernel, best at 3.5 TB/s read) with
// 2x block turnover: 8192 blocks x 256, 4 NT loads/thread (64 B/thread).
// Testing whether block-tail turnover buys the last few us; if total >= 200
// this is the read-path roofline (80% of dur_us is fixed harness overhead).
static constexpr long long PER_BATCH = 128LL * 256 * 256;   // 8,388,608 elems
static constexpr long long N_TOTAL   = 2 * PER_BATCH;       // 16,777,216

static constexpr int TPB    = 256;
static constexpr int BLOCKS = 8192;
static constexpr int T2     = BLOCKS * TPB;                 // 2,097,152 threads
// y_true: 4,194,304 vec4 = 2*T2 -> 2 t-loads/thread at stride T2.
// y_pred ch1 per batch: 2,097,152 vec4 = T2 -> 1 p-load/thread per batch.
// t[i] covers flat vec-index tid + i*T2; p[0]=batch0 ch1, p[1]=batch1 ch1.

typedef float v4f __attribute__((ext_vector_type(4)));
typedef int   v4i __attribute__((ext_vector_type(4)));

__global__ __launch_bounds__(TPB) void _cm_count_kernel(
        const float* __restrict__ y_pred,
        const int*   __restrict__ y_true,
        unsigned int* __restrict__ partials) {   // [3][BLOCKS]
    const int tid = blockIdx.x * TPB + threadIdx.x;

    const v4i* __restrict__ tv = reinterpret_cast<const v4i*>(y_true);
    const v4f* __restrict__ p0 = reinterpret_cast<const v4f*>(y_pred + PER_BATCH);      // b0 ch1
    const v4f* __restrict__ p1 = reinterpret_cast<const v4f*>(y_pred + 3 * PER_BATCH);  // b1 ch1

    // 4 nontemporal 16B loads, issued back-to-back.
    v4i t[2];
    v4f p[2];
    t[0] = __builtin_nontemporal_load(&tv[tid]);
    t[1] = __builtin_nontemporal_load(&tv[tid + T2]);
    p[0] = __builtin_nontemporal_load(&p0[tid]);
    p[1] = __builtin_nontemporal_load(&p1[tid]);

    unsigned int ct = 0, cp = 0, cb = 0;
    #pragma unroll
    for (int i = 0; i < 2; ++i) {
        unsigned int t0 = (t[i].x == 1), t1 = (t[i].y == 1),
                     t2 = (t[i].z == 1), t3 = (t[i].w == 1);
        unsigned int q0 = (p[i].x > 0.5f), q1 = (p[i].y > 0.5f),
                     q2 = (p[i].z > 0.5f), q3 = (p[i].w > 0.5f);
        ct += t0 + t1 + t2 + t3;
        cp += q0 + q1 + q2 + q3;
        cb += (t0 & q0) + (t1 & q1) + (t2 & q2) + (t3 & q3);
    }

    // wave64 shuffle reduction, then per-block partial store (no atomics).
    #pragma unroll
    for (int off = 32; off > 0; off >>= 1) {
        ct += __shfl_down(ct, off);
        cp += __shfl_down(cp, off);
        cb += __shfl_down(cb, off);
    }
    __shared__ unsigned int s[3][4];
    const int wave = threadIdx.x >> 6;
    if ((threadIdx.x & 63) == 0) { s[0][wave] = ct; s[1][wave] = cp; s[2][wave] = cb; }
    __syncthreads();
    if (threadIdx.x == 0) {
        partials[             blockIdx.x] = s[0][0] + s[0][1] + s[0][2] + s[0][3];
        partials[    BLOCKS + blockIdx.x] = s[1][0] + s[1][1] + s[1][2] + s[1][3];
        partials[2 * BLOCKS + blockIdx.x] = s[2][0] + s[2][1] + s[2][2] + s[2][3];
    }
}

__global__ __launch_bounds__(TPB) void _cm_finalize_kernel(
        const unsigned int* __restrict__ partials,
        int* __restrict__ out) {
    unsigned int ct = 0, cp = 0, cb = 0;
    #pragma unroll
    for (int i = 0; i < BLOCKS / TPB; ++i) {
        ct += partials[             threadIdx.x + i * TPB];
        cp += partials[    BLOCKS + threadIdx.x + i * TPB];
        cb += partials[2 * BLOCKS + threadIdx.x + i * TPB];
    }
    #pragma unroll
    for (int off = 32; off > 0; off >>= 1) {
        ct += __shfl_down(ct, off);
        cp += __shfl_down(cp, off);
        cb += __shfl_down(cb, off);
    }
    __shared__ unsigned int s[3][4];
    const int wave = threadIdx.x >> 6;
    if ((threadIdx.x & 63) == 0) { s[0][wave] = ct; s[1][wave] = cp; s[2][wave] = cb; }
    __syncthreads();
    if (threadIdx.x == 0) {
        int fct = (int)(s[0][0] + s[0][1] + s[0][2] + s[0][3]);
        int fcp = (int)(s[1][0] + s[1][1] + s[1][2] + s[1][3]);
        int fcb = (int)(s[2][0] + s[2][1] + s[2][2] + s[2][3]);
        int cm11 = fcb;
        int cm10 = fct - fcb;
        int cm01 = fcp - fcb;
        int cm00 = (int)N_TOTAL - fct - fcp + fcb;
        out[0] = cm00; out[1] = cm01;
        out[2] = cm10; out[3] = cm11;
        out[4] = cm11;   // tps[1]
        out[5] = cm01;   // fps[1]
        out[6] = cm10;   // fns[1]
        out[7] = cm00;   // tns[1]
    }
}

extern "C" void kernel_launch(void* const* d_in, const int* in_sizes, int n_in,
                              void* d_out, int out_size, void* d_ws, size_t ws_size,
                              hipStream_t stream) {
    const float* y_pred = (const float*)d_in[0];
    const int*   y_true = (const int*)d_in[1];
    unsigned int* partials = (unsigned int*)d_ws;   // 3*BLOCKS u32, fully overwritten
    int* out = (int*)d_out;

    _cm_count_kernel<<<BLOCKS, TPB, 0, stream>>>(y_pred, y_true, partials);
    _cm_finalize_kernel<<<1, TPB, 0, stream>>>(partials, out);
}